// Round 7
// baseline (178.856 us; speedup 1.0000x reference)
//
#include <hip/hip_runtime.h>

// SAGAN self-attention, B=4 C=256 H=W=64 (N=4096), CK=32.
//   f = fw@x+fb, g = gw@x+gb, hv = hw@x+hb         (channel 1x1 convs)
//   s[j,m] = sum_k f[k,j] g[k,m]
//   L[j]   = sum_m exp(s[j,m])
//   sa[c,m]= sum_j hv[c,j] * exp(s[j,m] - ln L[j])
//   out    = gamma*sa + x
//
// ws layout (bytes) — total 10,764,288:
//   fgT  [4][4096][64]  bf16  @ 0         (2,097,152)  [n][o]: o<32=f^T, o>=32=g^T
//   hv   [4][256][4096] bf16  @ 2097152   (8,388,608)
//   Lp   [4][4][4096]   f32   @ 10485760  (262,144)    partial L sums (4 m-splits)
//   lnL  [4][4096]      f32   @ 10747904  (65,536)
//
// All big grids use the bijective XCD map (grid%8==0): b = (bid&7)>>1 pins each
// batch's fgT (0.5MB) + hv (2MB) to one XCD pair's 8MB L2 for the whole chain.

typedef __bf16 bf16x4 __attribute__((ext_vector_type(4)));
typedef __bf16 bf16x8 __attribute__((ext_vector_type(8)));
typedef float  f32x4  __attribute__((ext_vector_type(4)));

static __device__ __forceinline__ bf16x8 frag_cat(bf16x4 lo, bf16x4 hi) {
  bf16x8 r;
  r[0]=lo[0]; r[1]=lo[1]; r[2]=lo[2]; r[3]=lo[3];
  r[4]=hi[0]; r[5]=hi[1]; r[6]=hi[2]; r[7]=hi[3];
  return r;
}
static __device__ __forceinline__ bf16x8 cvt8(f32x4 lo, f32x4 hi) {
  bf16x8 r;
  r[0]=(__bf16)lo[0]; r[1]=(__bf16)lo[1]; r[2]=(__bf16)lo[2]; r[3]=(__bf16)lo[3];
  r[4]=(__bf16)hi[0]; r[5]=(__bf16)hi[1]; r[6]=(__bf16)hi[2]; r[7]=(__bf16)hi[3];
  return r;
}
// kappa k-map (MANDATORY wherever the k-axis is tied to an MFMA D output):
//   element e -> k = h*4 + (e&3) + 16*(e>>2)          (h = lane>>4)
// Free axes (channel contraction) use the contiguous map e -> k = h*8 + e
// (single 16B load). Valid as long as A and B of one MFMA share the map.

// ---------------- proj: x read ONCE; block = 64 n-cols x all 320 m-rows ----------
__global__ __launch_bounds__(512, 1) void k_proj(
    const float* __restrict__ fw, const float* __restrict__ gw,
    const float* __restrict__ hw, const float* __restrict__ x,
    const float* __restrict__ fb, const float* __restrict__ gb,
    const float* __restrict__ hb,
    __bf16* __restrict__ fgT, __bf16* __restrict__ hv) {
  __shared__ __bf16 Bs[2][64][40];   // 10,240 B
  const int bid = blockIdx.x;
  const int b = (bid & 7) >> 1;
  const int n0 = (((bid >> 3) << 1) | (bid & 1)) * 64;
  const int t = threadIdx.x, w = t >> 6, lane = t & 63, r16 = lane & 15, h = lane >> 4;
  const int nsub = w & 1, mq = w >> 1;
  const float* xb = x + (size_t)b * (256 * 4096);
  const float* Wp[5];
  #pragma unroll
  for (int mt = 0; mt < 5; ++mt) {
    const int wrow = mq * 80 + mt * 16 + r16;
    Wp[mt] = wrow < 32 ? (fw + wrow * 256)
           : wrow < 64 ? (gw + (wrow - 32) * 256)
                       : (hw + (wrow - 64) * 256);
  }
  const int kk = t >> 4, nc = (t & 15) * 4;
  f32x4 acc[5][2] = {};
  {
    f32x4 xv = *(const f32x4*)&xb[(size_t)kk * 4096 + n0 + nc];
    Bs[0][nc + 0][kk] = (__bf16)xv[0]; Bs[0][nc + 1][kk] = (__bf16)xv[1];
    Bs[0][nc + 2][kk] = (__bf16)xv[2]; Bs[0][nc + 3][kk] = (__bf16)xv[3];
  }
  __syncthreads();
  for (int ks = 0; ks < 8; ++ks) {
    const int cur = ks & 1;
    f32x4 xn;
    if (ks < 7) xn = *(const f32x4*)&xb[(size_t)((ks + 1) * 32 + kk) * 4096 + n0 + nc];
    bf16x8 bf0 = *(const bf16x8*)&Bs[cur][nsub * 32 + r16][h * 8];
    bf16x8 bf1 = *(const bf16x8*)&Bs[cur][nsub * 32 + 16 + r16][h * 8];
    #pragma unroll
    for (int mt = 0; mt < 5; ++mt) {
      f32x4 wlo = *(const f32x4*)(Wp[mt] + ks * 32 + h * 8);
      f32x4 whi = *(const f32x4*)(Wp[mt] + ks * 32 + h * 8 + 4);
      bf16x8 af = cvt8(wlo, whi);
      acc[mt][0] = __builtin_amdgcn_mfma_f32_16x16x32_bf16(af, bf0, acc[mt][0], 0, 0, 0);
      acc[mt][1] = __builtin_amdgcn_mfma_f32_16x16x32_bf16(af, bf1, acc[mt][1], 0, 0, 0);
    }
    if (ks < 7) {
      const int nxt = cur ^ 1;
      Bs[nxt][nc + 0][kk] = (__bf16)xn[0]; Bs[nxt][nc + 1][kk] = (__bf16)xn[1];
      Bs[nxt][nc + 2][kk] = (__bf16)xn[2]; Bs[nxt][nc + 3][kk] = (__bf16)xn[3];
    }
    __syncthreads();
  }
  #pragma unroll
  for (int mt = 0; mt < 5; ++mt) {
    #pragma unroll
    for (int nt = 0; nt < 2; ++nt) {
      const int nn = n0 + nsub * 32 + nt * 16 + r16;
      #pragma unroll
      for (int r = 0; r < 4; ++r) {
        const int row = mq * 80 + mt * 16 + h * 4 + r;  // C/D: row=(lane>>4)*4+reg
        const float bias = row < 32 ? fb[row] : (row < 64 ? gb[row - 32] : hb[row - 64]);
        const float val = acc[mt][nt][r] + bias;
        if (row < 64) fgT[((size_t)b * 4096 + nn) * 64 + row] = (__bf16)val;
        else          hv[((size_t)b * 256 + (row - 64)) * 4096 + nn] = (__bf16)val;
      }
    }
  }
}

// ---------------- pass1: L[i] = sum_m exp(f_i . g_m)  (partial over m-quarter) ----
__global__ __launch_bounds__(256) void k_pass1(const __bf16* __restrict__ fgT,
                                               float* __restrict__ Lp) {
  const int bid = blockIdx.x;
  const int b = (bid & 7) >> 1;
  const int sub = ((bid >> 3) << 1) | (bid & 1);   // 0..255
  const int ms = sub >> 6, ib = sub & 63;
  const int w = threadIdx.x >> 6, lane = threadIdx.x & 63, r16 = lane & 15, h = lane >> 4;
  const int ibase = ib * 64 + w * 16;
  const __bf16* fg = fgT + (size_t)b * (4096 * 64);
  const bf16x8 afrag = *(const bf16x8*)(fg + (size_t)(ibase + r16) * 64 + h * 8);
  const f32x4 zero = {};
  float ls0 = 0.f, ls1 = 0.f, ls2 = 0.f, ls3 = 0.f;
  for (int mt = 0; mt < 64; mt += 2) {
    const int mb = ms * 1024 + mt * 16;
    bf16x8 g0 = *(const bf16x8*)(fg + (size_t)(mb + r16) * 64 + 32 + h * 8);
    bf16x8 g1 = *(const bf16x8*)(fg + (size_t)(mb + 16 + r16) * 64 + 32 + h * 8);
    f32x4 d0 = __builtin_amdgcn_mfma_f32_16x16x32_bf16(afrag, g0, zero, 0, 0, 0);
    f32x4 d1 = __builtin_amdgcn_mfma_f32_16x16x32_bf16(afrag, g1, zero, 0, 0, 0);
    ls0 += __expf(d0[0]) + __expf(d1[0]); ls1 += __expf(d0[1]) + __expf(d1[1]);
    ls2 += __expf(d0[2]) + __expf(d1[2]); ls3 += __expf(d0[3]) + __expf(d1[3]);
  }
  #pragma unroll
  for (int off = 1; off < 16; off <<= 1) {
    ls0 += __shfl_xor(ls0, off); ls1 += __shfl_xor(ls1, off);
    ls2 += __shfl_xor(ls2, off); ls3 += __shfl_xor(ls3, off);
  }
  if (r16 == 0) {
    f32x4 o = {ls0, ls1, ls2, ls3};
    *(f32x4*)&Lp[(size_t)(b * 4 + ms) * 4096 + ibase + h * 4] = o;
  }
}

// ---------------- lfin: lnL[b][j] = log(sum of 4 Lp partials) ----------------
__global__ __launch_bounds__(256) void k_lfin(const float* __restrict__ Lp,
                                              float* __restrict__ lnL) {
  const int e = (blockIdx.x * 256 + threadIdx.x) * 4;   // 16384 f32 outputs
  const int b = e >> 12, j = e & 4095;
  const float* lp = Lp + (size_t)b * (4 * 4096) + j;
  f32x4 L = *(const f32x4*)lp;
  L += *(const f32x4*)(lp + 4096);
  L += *(const f32x4*)(lp + 8192);
  L += *(const f32x4*)(lp + 12288);
  f32x4 o = {__logf(L[0]), __logf(L[1]), __logf(L[2]), __logf(L[3])};
  *(f32x4*)&lnL[b * 4096 + j] = o;
}

// ---------------- pass2: sa[c,m] = sum_j hv[c,j] exp(s[j,m]-lnL[j]); out=gm*sa+x --
// 1024 threads = 16 waves = 4 waves/SIMD (latency hiding: R5 was convoy-bound at
// 2 waves/SIMD). Wave = (chalf 0..3, msub, jh): 64c x 32m x 32j per iter.
// LDS [2][256][64] bf16, byte-col ^= 16*(row&7): reads 4/bank, writes 8/bank
// (both the b64/b128 structural floor). j-tile 64, double-buffered, T14 split.
// MFMA1 D (rows j, cols m) after exp is IN-REGISTER the B-fragment of MFMA2
// under the kappa map k = h*4 + (e&3) + 16*(e>>2).
__global__ __launch_bounds__(1024, 4) void k_pass2(const __bf16* __restrict__ fgT,
    const __bf16* __restrict__ hv, const float* __restrict__ lnL,
    const float* __restrict__ x, const float* __restrict__ gamma,
    float* __restrict__ out) {
  __shared__ __bf16 wS[2][256][64];   // 65,536 B, swizzled
  const int bid = blockIdx.x;
  const int b = (bid & 7) >> 1;                     // XCD pair per batch
  const int mblk = ((bid >> 3) << 1) | (bid & 1);   // 0..63
  const int t = threadIdx.x, w = t >> 6, lane = t & 63, r16 = lane & 15, h = lane >> 4;
  const int jh = w & 1, msub = (w >> 1) & 1, chalf = w >> 2;
  const int mbase = mblk * 64 + msub * 32;
  const __bf16* fg = fgT + (size_t)b * (4096 * 64);
  const __bf16* wb = hv + (size_t)b * 256 * 4096;
  const float* lnb = lnL + b * 4096;
  // gfrags: MFMA1 B operands (contiguous channel map), invariant over j
  const bf16x8 gf0 = *(const bf16x8*)(fg + (size_t)(mbase + r16) * 64 + 32 + h * 8);
  const bf16x8 gf1 = *(const bf16x8*)(fg + (size_t)(mbase + 16 + r16) * 64 + 32 + h * 8);
  // staging: thread t covers row t>>2, 16 j-elems (32B) at (t&3)*16, as 2 b128
  const int srow = t >> 2, q = t & 3;
  const int sw = (srow & 7) << 4;                   // write-side XOR
  const __bf16* sgsrc = wb + (size_t)srow * 4096 + q * 16;
  char* sb0 = (char*)&wS[0][srow][0];
  char* sb1 = (char*)&wS[1][srow][0];
  const int c32 = q * 32;
  const int rsw = (r16 & 7) << 4;                   // read-side XOR
  const int jh64 = jh * 64, h8 = h * 8;

  f32x4 acc[4][2] = {};
  const f32x4 zero = {};

  // prologue: stage tile 0, load f frags + lnL chunks (own jh half) for tile 0
  *(uint4*)(sb0 + ((c32 +  0) ^ sw)) = *(const uint4*)(sgsrc);
  *(uint4*)(sb0 + ((c32 + 16) ^ sw)) = *(const uint4*)(sgsrc + 8);
  bf16x8 fq0 = *(const bf16x8*)(fg + (size_t)(jh * 32 + r16) * 64 + h * 8);
  bf16x8 fq1 = *(const bf16x8*)(fg + (size_t)(jh * 32 + 16 + r16) * 64 + h * 8);
  f32x4 ln0 = *(const f32x4*)(lnb + jh * 32 + h * 4);
  f32x4 ln1 = *(const f32x4*)(lnb + jh * 32 + 16 + h * 4);
  __syncthreads();

  for (int it = 0; it < 64; ++it) {
    const int cur = it & 1;
    const int jbn = (it + 1) * 64;
    uint4 pw0, pw1; bf16x8 nf0, nf1; f32x4 nl0, nl1;
    if (it < 63) {   // issue next-tile global loads early (L2-hot, hide under compute)
      pw0 = *(const uint4*)(sgsrc + jbn);
      pw1 = *(const uint4*)(sgsrc + jbn + 8);
      nf0 = *(const bf16x8*)(fg + (size_t)(jbn + jh * 32 + r16) * 64 + h * 8);
      nf1 = *(const bf16x8*)(fg + (size_t)(jbn + jh * 32 + 16 + r16) * 64 + h * 8);
      nl0 = *(const f32x4*)(lnb + jbn + jh * 32 + h * 4);
      nl1 = *(const f32x4*)(lnb + jbn + jh * 32 + 16 + h * 4);
    }
    // MFMA1 x4 + exp(s - lnL) -> ef0 (m-tile 0), ef1 (m-tile 1); kappa on j
    f32x4 d0 = __builtin_amdgcn_mfma_f32_16x16x32_bf16(fq0, gf0, zero, 0, 0, 0);
    f32x4 d1 = __builtin_amdgcn_mfma_f32_16x16x32_bf16(fq1, gf0, zero, 0, 0, 0);
    f32x4 d2 = __builtin_amdgcn_mfma_f32_16x16x32_bf16(fq0, gf1, zero, 0, 0, 0);
    f32x4 d3 = __builtin_amdgcn_mfma_f32_16x16x32_bf16(fq1, gf1, zero, 0, 0, 0);
    bf16x8 ef0, ef1;
    #pragma unroll
    for (int r = 0; r < 4; ++r) {
      ef0[r]     = (__bf16)__expf(d0[r] - ln0[r]);
      ef0[4 + r] = (__bf16)__expf(d1[r] - ln1[r]);
      ef1[r]     = (__bf16)__expf(d2[r] - ln0[r]);
      ef1[4 + r] = (__bf16)__expf(d3[r] - ln1[r]);
    }
    // MFMA2: 4 c-tiles (64c); one w-frag per ct feeds both m-accumulators
    #pragma unroll
    for (int ct = 0; ct < 4; ++ct) {
      const char* rp = (const char*)&wS[cur][chalf * 64 + ct * 16 + r16][0];
      bf16x8 a = frag_cat(*(const bf16x4*)(rp + ((jh64 + h8) ^ rsw)),
                          *(const bf16x4*)(rp + ((jh64 + h8 + 32) ^ rsw)));
      acc[ct][0] = __builtin_amdgcn_mfma_f32_16x16x32_bf16(a, ef0, acc[ct][0], 0, 0, 0);
      acc[ct][1] = __builtin_amdgcn_mfma_f32_16x16x32_bf16(a, ef1, acc[ct][1], 0, 0, 0);
    }
    if (it < 63) {   // write next tile into the other buffer
      char* sd = cur ? sb0 : sb1;
      *(uint4*)(sd + ((c32 +  0) ^ sw)) = pw0;
      *(uint4*)(sd + ((c32 + 16) ^ sw)) = pw1;
      fq0 = nf0; fq1 = nf1; ln0 = nl0; ln1 = nl1;
    }
    __syncthreads();
  }

  // jh reduction: jh=1 waves dump partials into wS (dead), jh=0 adds + epilogue.
  float* red = (float*)wS;
  const int region = (chalf * 2 + msub) * 2048;     // 8 regions x 8KB (floats)
  if (jh == 1) {
    #pragma unroll
    for (int ct = 0; ct < 4; ++ct)
      #pragma unroll
      for (int mt = 0; mt < 2; ++mt)
        *(f32x4*)&red[region + ((ct * 2 + mt) * 64 + lane) * 4] = acc[ct][mt];
  }
  __syncthreads();
  if (jh == 0) {
    const float gm = gamma[0];
    const float* xb = x + (size_t)b * (256 * 4096);
    float* ob = out + (size_t)b * (256 * 4096);
    #pragma unroll
    for (int ct = 0; ct < 4; ++ct) {
      #pragma unroll
      for (int mt = 0; mt < 2; ++mt) {
        f32x4 o = *(const f32x4*)&red[region + ((ct * 2 + mt) * 64 + lane) * 4];
        o += acc[ct][mt];
        #pragma unroll
        for (int r = 0; r < 4; ++r) {
          const int c = chalf * 64 + ct * 16 + h * 4 + r;
          const size_t idx = (size_t)c * 4096 + (mbase + mt * 16 + r16);
          ob[idx] = gm * o[r] + xb[idx];
        }
      }
    }
  }
}

extern "C" void kernel_launch(void* const* d_in, const int* in_sizes, int n_in,
                              void* d_out, int out_size, void* d_ws, size_t ws_size,
                              hipStream_t stream) {
  const float* x     = (const float*)d_in[0];
  const float* fw    = (const float*)d_in[1];
  const float* fb    = (const float*)d_in[2];
  const float* gw    = (const float*)d_in[3];
  const float* gb    = (const float*)d_in[4];
  const float* hw    = (const float*)d_in[5];
  const float* hb    = (const float*)d_in[6];
  const float* gamma = (const float*)d_in[7];
  float* out = (float*)d_out;

  char* wsb = (char*)d_ws;
  __bf16* fgT = (__bf16*)(wsb);
  __bf16* hv  = (__bf16*)(wsb + 2097152);
  float*  Lp  = (float*) (wsb + 10485760);
  float*  lnL = (float*) (wsb + 10747904);

  k_proj<<<dim3(256), dim3(512), 0, stream>>>(fw, gw, hw, x, fb, gb, hb, fgT, hv);
  k_pass1<<<dim3(1024), dim3(256), 0, stream>>>(fgT, Lp);
  k_lfin<<<dim3(16), dim3(256), 0, stream>>>(Lp, lnL);
  k_pass2<<<dim3(256), dim3(1024), 0, stream>>>(fgT, hv, lnL, x, gamma, out);
}

// Round 8
// 160.298 us; speedup vs baseline: 1.1158x; 1.1158x over previous
//
#include <hip/hip_runtime.h>

// SAGAN self-attention, B=4 C=256 H=W=64 (N=4096), CK=32.
//   f = fw@x+fb, g = gw@x+gb, hv = hw@x+hb         (channel 1x1 convs)
//   s[j,m] = sum_k f[k,j] g[k,m]
//   L[j]   = sum_m exp(s[j,m])
//   sa[c,m]= sum_j hv[c,j] * exp(s[j,m] - ln L[j])
//   out    = gamma*sa + x
//
// ws layout (bytes) — total 10,764,288:
//   fgT  [4][4096][64]  bf16  @ 0         (2,097,152)  [n][o]: o<32=f^T, o>=32=g^T
//   hv   [4][256][4096] bf16  @ 2097152   (8,388,608)
//   Lp   [4][4][4096]   f32   @ 10485760  (262,144)    partial L sums (4 m-splits)
//   lnL  [4][4096]      f32   @ 10747904  (65,536)
//
// All big grids use the bijective XCD map (grid%8==0): b = (bid&7)>>1 pins each
// batch's fgT (0.5MB) + hv (2MB) to one XCD pair's 8MB L2 for the whole chain.

typedef __bf16 bf16x4 __attribute__((ext_vector_type(4)));
typedef __bf16 bf16x8 __attribute__((ext_vector_type(8)));
typedef float  f32x4  __attribute__((ext_vector_type(4)));

static __device__ __forceinline__ bf16x8 frag_cat(bf16x4 lo, bf16x4 hi) {
  bf16x8 r;
  r[0]=lo[0]; r[1]=lo[1]; r[2]=lo[2]; r[3]=lo[3];
  r[4]=hi[0]; r[5]=hi[1]; r[6]=hi[2]; r[7]=hi[3];
  return r;
}
static __device__ __forceinline__ bf16x8 cvt8(f32x4 lo, f32x4 hi) {
  bf16x8 r;
  r[0]=(__bf16)lo[0]; r[1]=(__bf16)lo[1]; r[2]=(__bf16)lo[2]; r[3]=(__bf16)lo[3];
  r[4]=(__bf16)hi[0]; r[5]=(__bf16)hi[1]; r[6]=(__bf16)hi[2]; r[7]=(__bf16)hi[3];
  return r;
}
// kappa k-map (MANDATORY wherever the k-axis is tied to an MFMA D output):
//   element e -> k = h*4 + (e&3) + 16*(e>>2)          (h = lane>>4)
// Free axes (channel contraction) use the contiguous map e -> k = h*8 + e
// (single 16B load). Valid as long as A and B of one MFMA share the map.

// ---------------- proj: x read ONCE; block = 64 n-cols x all 320 m-rows ----------
__global__ __launch_bounds__(512, 1) void k_proj(
    const float* __restrict__ fw, const float* __restrict__ gw,
    const float* __restrict__ hw, const float* __restrict__ x,
    const float* __restrict__ fb, const float* __restrict__ gb,
    const float* __restrict__ hb,
    __bf16* __restrict__ fgT, __bf16* __restrict__ hv) {
  __shared__ __bf16 Bs[2][64][40];   // 10,240 B
  const int bid = blockIdx.x;
  const int b = (bid & 7) >> 1;
  const int n0 = (((bid >> 3) << 1) | (bid & 1)) * 64;
  const int t = threadIdx.x, w = t >> 6, lane = t & 63, r16 = lane & 15, h = lane >> 4;
  const int nsub = w & 1, mq = w >> 1;
  const float* xb = x + (size_t)b * (256 * 4096);
  const float* Wp[5];
  #pragma unroll
  for (int mt = 0; mt < 5; ++mt) {
    const int wrow = mq * 80 + mt * 16 + r16;
    Wp[mt] = wrow < 32 ? (fw + wrow * 256)
           : wrow < 64 ? (gw + (wrow - 32) * 256)
                       : (hw + (wrow - 64) * 256);
  }
  const int kk = t >> 4, nc = (t & 15) * 4;
  f32x4 acc[5][2] = {};
  {
    f32x4 xv = *(const f32x4*)&xb[(size_t)kk * 4096 + n0 + nc];
    Bs[0][nc + 0][kk] = (__bf16)xv[0]; Bs[0][nc + 1][kk] = (__bf16)xv[1];
    Bs[0][nc + 2][kk] = (__bf16)xv[2]; Bs[0][nc + 3][kk] = (__bf16)xv[3];
  }
  __syncthreads();
  for (int ks = 0; ks < 8; ++ks) {
    const int cur = ks & 1;
    f32x4 xn;
    if (ks < 7) xn = *(const f32x4*)&xb[(size_t)((ks + 1) * 32 + kk) * 4096 + n0 + nc];
    bf16x8 bf0 = *(const bf16x8*)&Bs[cur][nsub * 32 + r16][h * 8];
    bf16x8 bf1 = *(const bf16x8*)&Bs[cur][nsub * 32 + 16 + r16][h * 8];
    #pragma unroll
    for (int mt = 0; mt < 5; ++mt) {
      f32x4 wlo = *(const f32x4*)(Wp[mt] + ks * 32 + h * 8);
      f32x4 whi = *(const f32x4*)(Wp[mt] + ks * 32 + h * 8 + 4);
      bf16x8 af = cvt8(wlo, whi);
      acc[mt][0] = __builtin_amdgcn_mfma_f32_16x16x32_bf16(af, bf0, acc[mt][0], 0, 0, 0);
      acc[mt][1] = __builtin_amdgcn_mfma_f32_16x16x32_bf16(af, bf1, acc[mt][1], 0, 0, 0);
    }
    if (ks < 7) {
      const int nxt = cur ^ 1;
      Bs[nxt][nc + 0][kk] = (__bf16)xn[0]; Bs[nxt][nc + 1][kk] = (__bf16)xn[1];
      Bs[nxt][nc + 2][kk] = (__bf16)xn[2]; Bs[nxt][nc + 3][kk] = (__bf16)xn[3];
    }
    __syncthreads();
  }
  #pragma unroll
  for (int mt = 0; mt < 5; ++mt) {
    #pragma unroll
    for (int nt = 0; nt < 2; ++nt) {
      const int nn = n0 + nsub * 32 + nt * 16 + r16;
      #pragma unroll
      for (int r = 0; r < 4; ++r) {
        const int row = mq * 80 + mt * 16 + h * 4 + r;  // C/D: row=(lane>>4)*4+reg
        const float bias = row < 32 ? fb[row] : (row < 64 ? gb[row - 32] : hb[row - 64]);
        const float val = acc[mt][nt][r] + bias;
        if (row < 64) fgT[((size_t)b * 4096 + nn) * 64 + row] = (__bf16)val;
        else          hv[((size_t)b * 256 + (row - 64)) * 4096 + nn] = (__bf16)val;
      }
    }
  }
}

// ---------------- pass1: L[i] = sum_m exp(f_i . g_m)  (partial over m-quarter) ----
__global__ __launch_bounds__(256) void k_pass1(const __bf16* __restrict__ fgT,
                                               float* __restrict__ Lp) {
  const int bid = blockIdx.x;
  const int b = (bid & 7) >> 1;
  const int sub = ((bid >> 3) << 1) | (bid & 1);   // 0..255
  const int ms = sub >> 6, ib = sub & 63;
  const int w = threadIdx.x >> 6, lane = threadIdx.x & 63, r16 = lane & 15, h = lane >> 4;
  const int ibase = ib * 64 + w * 16;
  const __bf16* fg = fgT + (size_t)b * (4096 * 64);
  const bf16x8 afrag = *(const bf16x8*)(fg + (size_t)(ibase + r16) * 64 + h * 8);
  const f32x4 zero = {};
  float ls0 = 0.f, ls1 = 0.f, ls2 = 0.f, ls3 = 0.f;
  for (int mt = 0; mt < 64; mt += 2) {
    const int mb = ms * 1024 + mt * 16;
    bf16x8 g0 = *(const bf16x8*)(fg + (size_t)(mb + r16) * 64 + 32 + h * 8);
    bf16x8 g1 = *(const bf16x8*)(fg + (size_t)(mb + 16 + r16) * 64 + 32 + h * 8);
    f32x4 d0 = __builtin_amdgcn_mfma_f32_16x16x32_bf16(afrag, g0, zero, 0, 0, 0);
    f32x4 d1 = __builtin_amdgcn_mfma_f32_16x16x32_bf16(afrag, g1, zero, 0, 0, 0);
    ls0 += __expf(d0[0]) + __expf(d1[0]); ls1 += __expf(d0[1]) + __expf(d1[1]);
    ls2 += __expf(d0[2]) + __expf(d1[2]); ls3 += __expf(d0[3]) + __expf(d1[3]);
  }
  #pragma unroll
  for (int off = 1; off < 16; off <<= 1) {
    ls0 += __shfl_xor(ls0, off); ls1 += __shfl_xor(ls1, off);
    ls2 += __shfl_xor(ls2, off); ls3 += __shfl_xor(ls3, off);
  }
  if (r16 == 0) {
    f32x4 o = {ls0, ls1, ls2, ls3};
    *(f32x4*)&Lp[(size_t)(b * 4 + ms) * 4096 + ibase + h * 4] = o;
  }
}

// ---------------- lfin: lnL[b][j] = log(sum of 4 Lp partials) ----------------
__global__ __launch_bounds__(256) void k_lfin(const float* __restrict__ Lp,
                                              float* __restrict__ lnL) {
  const int e = (blockIdx.x * 256 + threadIdx.x) * 4;   // 16384 f32 outputs
  const int b = e >> 12, j = e & 4095;
  const float* lp = Lp + (size_t)b * (4 * 4096) + j;
  f32x4 L = *(const f32x4*)lp;
  L += *(const f32x4*)(lp + 4096);
  L += *(const f32x4*)(lp + 8192);
  L += *(const f32x4*)(lp + 12288);
  f32x4 o = {__logf(L[0]), __logf(L[1]), __logf(L[2]), __logf(L[3])};
  *(f32x4*)&lnL[b * 4096 + j] = o;
}

// ---------------- pass2: sa[c,m] = sum_j hv[c,j] exp(s[j,m]-lnL[j]); out=gm*sa+x --
// 1024 blocks x 256 threads (4 blocks/CU): block = 64 c-rows x 64 m-cols.
// R6 lesson: the 16-wave single-block barrier convoyed everything; the data
// flow is closed within a c-quarter, so make each quarter an independent block
// — 4-wave barriers + cross-block overlap hides load latency and LDS stalls.
// Waves = (msub, jh): 64c x 32m x 32j each. LDS [2][64][64] bf16 swizzled
// (byte-col ^= 16*(row&7)): reads 4 lanes/bank, writes 8/bank (b64/b128 floor).
// MFMA1 D (rows j, cols m) after exp is IN-REGISTER the B-fragment of MFMA2
// under the kappa map k = h*4 + (e&3) + 16*(e>>2).
__global__ __launch_bounds__(256, 4) void k_pass2(const __bf16* __restrict__ fgT,
    const __bf16* __restrict__ hv, const float* __restrict__ lnL,
    const float* __restrict__ x, const float* __restrict__ gamma,
    float* __restrict__ out) {
  __shared__ __bf16 wS[2][64][64];   // 16,384 B, swizzled
  const int bid = blockIdx.x;
  const int b = (bid & 7) >> 1;                     // XCD pair per batch
  const int cq = (bid >> 3) & 3;                    // c-quarter: rows cq*64..+63
  const int mblk = ((bid >> 5) << 1) | (bid & 1);   // 0..63
  const int t = threadIdx.x, w = t >> 6, lane = t & 63, r16 = lane & 15, h = lane >> 4;
  const int jh = w & 1, msub = w >> 1;
  const int mbase = mblk * 64 + msub * 32;
  const __bf16* fg = fgT + (size_t)b * (4096 * 64);
  const __bf16* wb = hv + ((size_t)b * 256 + cq * 64) * 4096;
  const float* lnb = lnL + b * 4096;
  // gfrags: MFMA1 B operands (contiguous channel map), invariant over j
  const bf16x8 gf0 = *(const bf16x8*)(fg + (size_t)(mbase + r16) * 64 + 32 + h * 8);
  const bf16x8 gf1 = *(const bf16x8*)(fg + (size_t)(mbase + 16 + r16) * 64 + 32 + h * 8);
  // staging: thread t covers row t>>2 (of 64), 16 j-elems (32B) at (t&3)*16
  const int srow = t >> 2, q = t & 3;
  const int sw = (srow & 7) << 4;                   // write-side XOR
  const __bf16* sgsrc = wb + (size_t)srow * 4096 + q * 16;
  char* sb0 = (char*)&wS[0][srow][0];
  char* sb1 = (char*)&wS[1][srow][0];
  const int c32 = q * 32;
  const int rsw = (r16 & 7) << 4;                   // read-side XOR
  const int jh64 = jh * 64, h8 = h * 8;

  f32x4 acc[4][2] = {};
  const f32x4 zero = {};

  // prologue: stage tile 0, load f frags + lnL chunks (own jh half) for tile 0
  *(uint4*)(sb0 + ((c32 +  0) ^ sw)) = *(const uint4*)(sgsrc);
  *(uint4*)(sb0 + ((c32 + 16) ^ sw)) = *(const uint4*)(sgsrc + 8);
  bf16x8 fq0 = *(const bf16x8*)(fg + (size_t)(jh * 32 + r16) * 64 + h * 8);
  bf16x8 fq1 = *(const bf16x8*)(fg + (size_t)(jh * 32 + 16 + r16) * 64 + h * 8);
  f32x4 ln0 = *(const f32x4*)(lnb + jh * 32 + h * 4);
  f32x4 ln1 = *(const f32x4*)(lnb + jh * 32 + 16 + h * 4);
  __syncthreads();

  for (int it = 0; it < 64; ++it) {
    const int cur = it & 1;
    const int jbn = (it + 1) * 64;
    uint4 pw0, pw1; bf16x8 nf0, nf1; f32x4 nl0, nl1;
    if (it < 63) {   // issue next-tile global loads early (L2-hot, hide under compute)
      pw0 = *(const uint4*)(sgsrc + jbn);
      pw1 = *(const uint4*)(sgsrc + jbn + 8);
      nf0 = *(const bf16x8*)(fg + (size_t)(jbn + jh * 32 + r16) * 64 + h * 8);
      nf1 = *(const bf16x8*)(fg + (size_t)(jbn + jh * 32 + 16 + r16) * 64 + h * 8);
      nl0 = *(const f32x4*)(lnb + jbn + jh * 32 + h * 4);
      nl1 = *(const f32x4*)(lnb + jbn + jh * 32 + 16 + h * 4);
    }
    // MFMA1 x4 + exp(s - lnL) -> ef0 (m-tile 0), ef1 (m-tile 1); kappa on j
    f32x4 d0 = __builtin_amdgcn_mfma_f32_16x16x32_bf16(fq0, gf0, zero, 0, 0, 0);
    f32x4 d1 = __builtin_amdgcn_mfma_f32_16x16x32_bf16(fq1, gf0, zero, 0, 0, 0);
    f32x4 d2 = __builtin_amdgcn_mfma_f32_16x16x32_bf16(fq0, gf1, zero, 0, 0, 0);
    f32x4 d3 = __builtin_amdgcn_mfma_f32_16x16x32_bf16(fq1, gf1, zero, 0, 0, 0);
    bf16x8 ef0, ef1;
    #pragma unroll
    for (int r = 0; r < 4; ++r) {
      ef0[r]     = (__bf16)__expf(d0[r] - ln0[r]);
      ef0[4 + r] = (__bf16)__expf(d1[r] - ln1[r]);
      ef1[r]     = (__bf16)__expf(d2[r] - ln0[r]);
      ef1[4 + r] = (__bf16)__expf(d3[r] - ln1[r]);
    }
    // MFMA2: 4 c-tiles (64c); one w-frag per ct feeds both m-accumulators
    #pragma unroll
    for (int ct = 0; ct < 4; ++ct) {
      const char* rp = (const char*)&wS[cur][ct * 16 + r16][0];
      bf16x8 a = frag_cat(*(const bf16x4*)(rp + ((jh64 + h8) ^ rsw)),
                          *(const bf16x4*)(rp + ((jh64 + h8 + 32) ^ rsw)));
      acc[ct][0] = __builtin_amdgcn_mfma_f32_16x16x32_bf16(a, ef0, acc[ct][0], 0, 0, 0);
      acc[ct][1] = __builtin_amdgcn_mfma_f32_16x16x32_bf16(a, ef1, acc[ct][1], 0, 0, 0);
    }
    if (it < 63) {   // write next tile into the other buffer
      char* sd = cur ? sb0 : sb1;
      *(uint4*)(sd + ((c32 +  0) ^ sw)) = pw0;
      *(uint4*)(sd + ((c32 + 16) ^ sw)) = pw1;
      fq0 = nf0; fq1 = nf1; ln0 = nl0; ln1 = nl1;
    }
    __syncthreads();
  }

  // jh reduction: jh=1 waves dump partials into wS (dead), jh=0 adds + epilogue.
  float* red = (float*)wS;
  const int region = msub * 2048;                   // 2 regions x 8KB (floats)
  if (jh == 1) {
    #pragma unroll
    for (int ct = 0; ct < 4; ++ct)
      #pragma unroll
      for (int mt = 0; mt < 2; ++mt)
        *(f32x4*)&red[region + ((ct * 2 + mt) * 64 + lane) * 4] = acc[ct][mt];
  }
  __syncthreads();
  if (jh == 0) {
    const float gm = gamma[0];
    const float* xb = x + (size_t)b * (256 * 4096);
    float* ob = out + (size_t)b * (256 * 4096);
    #pragma unroll
    for (int ct = 0; ct < 4; ++ct) {
      #pragma unroll
      for (int mt = 0; mt < 2; ++mt) {
        f32x4 o = *(const f32x4*)&red[region + ((ct * 2 + mt) * 64 + lane) * 4];
        o += acc[ct][mt];
        #pragma unroll
        for (int r = 0; r < 4; ++r) {
          const int c = cq * 64 + ct * 16 + h * 4 + r;
          const size_t idx = (size_t)c * 4096 + (mbase + mt * 16 + r16);
          ob[idx] = gm * o[r] + xb[idx];
        }
      }
    }
  }
}

extern "C" void kernel_launch(void* const* d_in, const int* in_sizes, int n_in,
                              void* d_out, int out_size, void* d_ws, size_t ws_size,
                              hipStream_t stream) {
  const float* x     = (const float*)d_in[0];
  const float* fw    = (const float*)d_in[1];
  const float* fb    = (const float*)d_in[2];
  const float* gw    = (const float*)d_in[3];
  const float* gb    = (const float*)d_in[4];
  const float* hw    = (const float*)d_in[5];
  const float* hb    = (const float*)d_in[6];
  const float* gamma = (const float*)d_in[7];
  float* out = (float*)d_out;

  char* wsb = (char*)d_ws;
  __bf16* fgT = (__bf16*)(wsb);
  __bf16* hv  = (__bf16*)(wsb + 2097152);
  float*  Lp  = (float*) (wsb + 10485760);
  float*  lnL = (float*) (wsb + 10747904);

  k_proj<<<dim3(256), dim3(512), 0, stream>>>(fw, gw, hw, x, fb, gb, hb, fgT, hv);
  k_pass1<<<dim3(1024), dim3(256), 0, stream>>>(fgT, Lp);
  k_lfin<<<dim3(16), dim3(256), 0, stream>>>(Lp, lnL);
  k_pass2<<<dim3(1024), dim3(256), 0, stream>>>(fgT, hv, lnL, x, gamma, out);
}